// Round 2
// baseline (397.325 us; speedup 1.0000x reference)
//
#include <hip/hip_runtime.h>
#include <hip/hip_bf16.h>
#include <stdint.h>

using bf16 = __hip_bfloat16;
typedef __attribute__((ext_vector_type(8))) short short8;     // 8 bf16 MFMA frag
typedef __attribute__((ext_vector_type(4))) float f32x4;      // MFMA acc
typedef __attribute__((ext_vector_type(4))) float float4v;
typedef __attribute__((ext_vector_type(4))) unsigned short us4;

#define LDS_U32 __attribute__((address_space(3))) uint32_t
#define GLB_U32 __attribute__((address_space(1))) uint32_t

__device__ __forceinline__ unsigned short f2b(float f) {
  union { float f; uint32_t u; } x; x.f = f;
  uint32_t r = x.u + 0x7FFFu + ((x.u >> 16) & 1u);  // RNE
  return (unsigned short)(r >> 16);
}

// ---------------- fp32 -> bf16 cast, up to 4 arrays in one launch ----------------
__global__ void cast_multi(const float* __restrict__ s0, const float* __restrict__ s1,
                           const float* __restrict__ s2, const float* __restrict__ s3,
                           bf16* __restrict__ d0, bf16* __restrict__ d1,
                           bf16* __restrict__ d2, bf16* __restrict__ d3,
                           int nvec, int narr) {
  int total = nvec * narr;
  for (int i = blockIdx.x * blockDim.x + threadIdx.x; i < total;
       i += gridDim.x * blockDim.x) {
    int a = i / nvec, vi = i - a * nvec;
    const float* s = (a == 0) ? s0 : (a == 1) ? s1 : (a == 2) ? s2 : s3;
    bf16* d = (a == 0) ? d0 : (a == 1) ? d1 : (a == 2) ? d2 : d3;
    float4v x = ((const float4v*)s)[vi];
    us4 y;
    y.x = f2b(x.x); y.y = f2b(x.y); y.z = f2b(x.z); y.w = f2b(x.w);
    ((us4*)d)[vi] = y;
  }
}

// ---------------- fused QKV projection: 128x64 tiles, bf16 in, fp32 acc ----------------
// seg 0: Qh = qb @ Wq^T (bf16 [4096,1024]); seg 1: Kh = kb @ Wk^T;
// seg 2: Vt[(b*1024 + col)][2048] = (vb @ Wv^T) transposed per-head.
__global__ __launch_bounds__(256, 2)
void qkv_proj(const bf16* __restrict__ Aq, const bf16* __restrict__ Ak,
              const bf16* __restrict__ Av,
              const bf16* __restrict__ Wq, const bf16* __restrict__ Wk,
              const bf16* __restrict__ Wv,
              bf16* __restrict__ Qh, bf16* __restrict__ Kh, bf16* __restrict__ Vt) {
  __shared__ bf16 Alds[128 * 64];
  __shared__ bf16 Blds[64 * 64];
  const int t = threadIdx.x, lane = t & 63, wave = t >> 6;
  const int l15 = lane & 15, l4 = lane >> 4;
  const int seg = blockIdx.x >> 4;
  const int n0 = (blockIdx.x & 15) * 64;
  const int m0 = blockIdx.y * 128;
  const bf16* A = (seg == 0) ? Aq : (seg == 1) ? Ak : Av;
  const bf16* B = (seg == 0) ? Wq : (seg == 1) ? Wk : Wv;
  const int K = 1024;
  const int wr = (wave >> 1) * 64, wc = (wave & 1) * 32;

  f32x4 acc[4][2] = {};

  for (int kt = 0; kt < K; kt += 64) {
#pragma unroll
    for (int i = 0; i < 4; ++i) {
      int f = i * 256 + t, row = f >> 3, csrc = (f & 7) ^ (row & 7);
      __builtin_amdgcn_global_load_lds(
          (const GLB_U32*)(A + (size_t)(m0 + row) * K + kt + csrc * 8),
          (LDS_U32*)(Alds + f * 8), 16, 0, 0);
    }
#pragma unroll
    for (int i = 0; i < 2; ++i) {
      int f = i * 256 + t, row = f >> 3, csrc = (f & 7) ^ (row & 7);
      __builtin_amdgcn_global_load_lds(
          (const GLB_U32*)(B + (size_t)(n0 + row) * K + kt + csrc * 8),
          (LDS_U32*)(Blds + f * 8), 16, 0, 0);
    }
    __syncthreads();
#pragma unroll
    for (int ks = 0; ks < 2; ++ks) {
      short8 af[4], bfr[2];
#pragma unroll
      for (int mi = 0; mi < 4; ++mi) {
        int row = wr + mi * 16 + l15;
        int ch = (ks * 4 + l4) ^ (row & 7);
        af[mi] = *(const short8*)(Alds + row * 64 + ch * 8);
      }
#pragma unroll
      for (int ni = 0; ni < 2; ++ni) {
        int row = wc + ni * 16 + l15;
        int ch = (ks * 4 + l4) ^ (row & 7);
        bfr[ni] = *(const short8*)(Blds + row * 64 + ch * 8);
      }
#pragma unroll
      for (int mi = 0; mi < 4; ++mi)
#pragma unroll
        for (int ni = 0; ni < 2; ++ni)
          acc[mi][ni] = __builtin_amdgcn_mfma_f32_16x16x32_bf16(
              af[mi], bfr[ni], acc[mi][ni], 0, 0, 0);
    }
    __syncthreads();
  }

#pragma unroll
  for (int mi = 0; mi < 4; ++mi) {
#pragma unroll
    for (int ni = 0; ni < 2; ++ni) {
      int rbase = m0 + wr + mi * 16 + l4 * 4;
      int col = n0 + wc + ni * 16 + l15;
      if (seg < 2) {
        unsigned short* C = (unsigned short*)((seg == 0) ? Qh : Kh);
#pragma unroll
        for (int r = 0; r < 4; ++r)
          C[(size_t)(rbase + r) * 1024 + col] = f2b(acc[mi][ni][r]);
      } else {
        unsigned short* C = (unsigned short*)Vt;
        int bb = rbase >> 11, s = rbase & 2047;
        size_t addr = ((size_t)(bb * 1024 + col)) * 2048 + s;
        us4 y;
        y.x = f2b(acc[mi][ni][0]); y.y = f2b(acc[mi][ni][1]);
        y.z = f2b(acc[mi][ni][2]); y.w = f2b(acc[mi][ni][3]);
        *(us4*)(C + addr) = y;
      }
    }
  }
}

// ---------------- output projection: fp32 out, 128x64 tiles ----------------
__global__ __launch_bounds__(256, 2)
void gemm_o(const bf16* __restrict__ A, const bf16* __restrict__ B,
            float* __restrict__ C) {
  __shared__ bf16 Alds[128 * 64];
  __shared__ bf16 Blds[64 * 64];
  const int t = threadIdx.x, lane = t & 63, wave = t >> 6;
  const int l15 = lane & 15, l4 = lane >> 4;
  const int n0 = blockIdx.x * 64, m0 = blockIdx.y * 128;
  const int K = 1024;
  const int wr = (wave >> 1) * 64, wc = (wave & 1) * 32;

  f32x4 acc[4][2] = {};

  for (int kt = 0; kt < K; kt += 64) {
#pragma unroll
    for (int i = 0; i < 4; ++i) {
      int f = i * 256 + t, row = f >> 3, csrc = (f & 7) ^ (row & 7);
      __builtin_amdgcn_global_load_lds(
          (const GLB_U32*)(A + (size_t)(m0 + row) * K + kt + csrc * 8),
          (LDS_U32*)(Alds + f * 8), 16, 0, 0);
    }
#pragma unroll
    for (int i = 0; i < 2; ++i) {
      int f = i * 256 + t, row = f >> 3, csrc = (f & 7) ^ (row & 7);
      __builtin_amdgcn_global_load_lds(
          (const GLB_U32*)(B + (size_t)(n0 + row) * K + kt + csrc * 8),
          (LDS_U32*)(Blds + f * 8), 16, 0, 0);
    }
    __syncthreads();
#pragma unroll
    for (int ks = 0; ks < 2; ++ks) {
      short8 af[4], bfr[2];
#pragma unroll
      for (int mi = 0; mi < 4; ++mi) {
        int row = wr + mi * 16 + l15;
        int ch = (ks * 4 + l4) ^ (row & 7);
        af[mi] = *(const short8*)(Alds + row * 64 + ch * 8);
      }
#pragma unroll
      for (int ni = 0; ni < 2; ++ni) {
        int row = wc + ni * 16 + l15;
        int ch = (ks * 4 + l4) ^ (row & 7);
        bfr[ni] = *(const short8*)(Blds + row * 64 + ch * 8);
      }
#pragma unroll
      for (int mi = 0; mi < 4; ++mi)
#pragma unroll
        for (int ni = 0; ni < 2; ++ni)
          acc[mi][ni] = __builtin_amdgcn_mfma_f32_16x16x32_bf16(
              af[mi], bfr[ni], acc[mi][ni], 0, 0, 0);
    }
    __syncthreads();
  }

#pragma unroll
  for (int mi = 0; mi < 4; ++mi)
#pragma unroll
    for (int ni = 0; ni < 2; ++ni) {
      int rbase = m0 + wr + mi * 16 + l4 * 4;
      int col = n0 + wc + ni * 16 + l15;
#pragma unroll
      for (int r = 0; r < 4; ++r)
        C[(size_t)(rbase + r) * 1024 + col] = acc[mi][ni][r];
    }
}

// ---------------- causal flash attention ----------------
// 16 q-rows per wave, 4 waves/block, heavy tiles dispatched first.
// Q,K: bf16 [B*S,1024]; Vt: bf16 [B*H][64][2048]; O: bf16 [B*S,1024].
__global__ __launch_bounds__(256, 2)
void attn_fwd(const bf16* __restrict__ Q, const bf16* __restrict__ K,
              const bf16* __restrict__ Vt, const int* __restrict__ mask,
              bf16* __restrict__ O) {
  const int b = blockIdx.z, h = blockIdx.y;
  const int qt = 31 - (int)blockIdx.x;  // heavy-first (LPT)
  const int t = threadIdx.x, wave = t >> 6, lane = t & 63;
  const int l15 = lane & 15, l4 = lane >> 4;
  const int q0 = qt * 64 + wave * 16;

  __shared__ float biasLds[2048];
  __shared__ bf16 PldsAll[4][16 * 72];  // +16B row pad -> conflict-light b128 reads
  for (int i = t; i < 2048; i += 256)
    biasLds[i] = mask[b * 2048 + i] ? 0.f : -1e9f;
  __syncthreads();
  bf16* Plds = PldsAll[wave];

  const size_t bqk = (size_t)b * 2048 * 1024 + h * 64;
  const size_t vbase = (size_t)(b * 16 + h) * 64 * 2048;
  const float SCL = 0.18033688f;  // 1/sqrt(64) * log2(e), exp2-domain softmax

  short8 qa[2];
#pragma unroll
  for (int ks = 0; ks < 2; ++ks)
    qa[ks] = *(const short8*)(Q + bqk + (size_t)(q0 + l15) * 1024 + ks * 32 + l4 * 8);

  f32x4 acc[4] = {};
  float mrun[4], lrun[4];
#pragma unroll
  for (int r = 0; r < 4; ++r) { mrun[r] = -1e30f; lrun[r] = 0.f; }

  const int kmax = q0 + 16;
  const int k0L = ((kmax - 1) >> 6) << 6;  // diagonal tile start

  short8 kb[4][2], vb[4][2];
#pragma unroll
  for (int kn = 0; kn < 4; ++kn)
#pragma unroll
    for (int ks = 0; ks < 2; ++ks)
      kb[kn][ks] = *(const short8*)(K + bqk + (size_t)(kn * 16 + l15) * 1024 +
                                    ks * 32 + l4 * 8);

  for (int k0 = 0;; k0 += 64) {
    // V loads for this tile: consumed at iteration end (hidden under QK+softmax)
#pragma unroll
    for (int nd = 0; nd < 4; ++nd)
#pragma unroll
      for (int ks = 0; ks < 2; ++ks)
        vb[nd][ks] = *(const short8*)(Vt + vbase + (size_t)(nd * 16 + l15) * 2048 +
                                      k0 + ks * 32 + l4 * 8);

    f32x4 sc[4] = {};
#pragma unroll
    for (int ks = 0; ks < 2; ++ks)
#pragma unroll
      for (int kn = 0; kn < 4; ++kn)
        sc[kn] = __builtin_amdgcn_mfma_f32_16x16x32_bf16(qa[ks], kb[kn][ks], sc[kn], 0, 0, 0);

    const bool more = (k0 < k0L);
    if (more) {  // prefetch next K tile right after consumption
#pragma unroll
      for (int kn = 0; kn < 4; ++kn)
#pragma unroll
        for (int ks = 0; ks < 2; ++ks)
          kb[kn][ks] = *(const short8*)(K + bqk +
                                        (size_t)(k0 + 64 + kn * 16 + l15) * 1024 +
                                        ks * 32 + l4 * 8);
    }

    float bofs[4];
#pragma unroll
    for (int kn = 0; kn < 4; ++kn) bofs[kn] = biasLds[k0 + kn * 16 + l15];

    if (k0 == k0L) {  // diagonal tile: causal compare only here
#pragma unroll
      for (int kn = 0; kn < 4; ++kn) {
        int kg = k0 + kn * 16 + l15;
#pragma unroll
        for (int r = 0; r < 4; ++r) {
          int qg = q0 + l4 * 4 + r;
          sc[kn][r] = (kg > qg) ? -1e9f : sc[kn][r] * SCL + bofs[kn];
        }
      }
    } else {
#pragma unroll
      for (int kn = 0; kn < 4; ++kn)
#pragma unroll
        for (int r = 0; r < 4; ++r) sc[kn][r] = sc[kn][r] * SCL + bofs[kn];
    }

#pragma unroll
    for (int r = 0; r < 4; ++r) {
      float mx = fmaxf(fmaxf(sc[0][r], sc[1][r]), fmaxf(sc[2][r], sc[3][r]));
      mx = fmaxf(mx, __shfl_xor(mx, 1));
      mx = fmaxf(mx, __shfl_xor(mx, 2));
      mx = fmaxf(mx, __shfl_xor(mx, 4));
      mx = fmaxf(mx, __shfl_xor(mx, 8));
      float mnew = fmaxf(mrun[r], mx);
      float corr = exp2f(mrun[r] - mnew);
      mrun[r] = mnew;
      float rs = 0.f;
#pragma unroll
      for (int kn = 0; kn < 4; ++kn) {
        float p = exp2f(sc[kn][r] - mnew);
        sc[kn][r] = p;
        rs += p;
      }
      rs += __shfl_xor(rs, 1);
      rs += __shfl_xor(rs, 2);
      rs += __shfl_xor(rs, 4);
      rs += __shfl_xor(rs, 8);
      lrun[r] = lrun[r] * corr + rs;
#pragma unroll
      for (int nd = 0; nd < 4; ++nd) acc[nd][r] *= corr;
    }

    // P (D-layout) -> LDS -> A-frag layout
#pragma unroll
    for (int kn = 0; kn < 4; ++kn)
#pragma unroll
      for (int r = 0; r < 4; ++r)
        ((unsigned short*)Plds)[(l4 * 4 + r) * 72 + kn * 16 + l15] = f2b(sc[kn][r]);

#pragma unroll
    for (int ks = 0; ks < 2; ++ks) {
      short8 pa = *(const short8*)(Plds + l15 * 72 + ks * 32 + l4 * 8);
#pragma unroll
      for (int nd = 0; nd < 4; ++nd)
        acc[nd] = __builtin_amdgcn_mfma_f32_16x16x32_bf16(pa, vb[nd][ks], acc[nd], 0, 0, 0);
    }
    if (!more) break;
  }

  float invr[4];
#pragma unroll
  for (int r = 0; r < 4; ++r) invr[r] = 1.0f / lrun[r];
#pragma unroll
  for (int nd = 0; nd < 4; ++nd)
#pragma unroll
    for (int r = 0; r < 4; ++r)
      ((unsigned short*)O)[bqk + (size_t)(q0 + l4 * 4 + r) * 1024 + nd * 16 + l15] =
          f2b(acc[nd][r] * invr[r]);
}

// ---------------- launch ----------------
extern "C" void kernel_launch(void* const* d_in, const int* in_sizes, int n_in,
                              void* d_out, int out_size, void* d_ws, size_t ws_size,
                              hipStream_t stream) {
  const float* q = (const float*)d_in[0];
  const float* k = (const float*)d_in[1];
  const float* v = (const float*)d_in[2];
  const int* mask = (const int*)d_in[3];
  const float* Wq = (const float*)d_in[4];
  const float* Wk = (const float*)d_in[5];
  const float* Wv = (const float*)d_in[6];
  const float* Wo = (const float*)d_in[7];
  float* out = (float*)d_out;

  const size_t NT = 4096 * 1024;
  const size_t NW = 1024 * 1024;
  bf16* p = (bf16*)d_ws;
  bf16* qb = p;  p += NT;
  bf16* kb = p;  p += NT;
  bf16* vb = p;  p += NT;
  bf16* Wqb = p; p += NW;
  bf16* Wkb = p; p += NW;
  bf16* Wvb = p; p += NW;
  bf16* Wob = p; p += NW;
  bf16* Qh = p;  p += NT;
  bf16* Kh = p;  p += NT;
  bf16* Vt = p;  p += NT;
  bf16* Oh = p;  p += NT;

  cast_multi<<<2048, 256, 0, stream>>>(q, k, v, nullptr, qb, kb, vb, nullptr,
                                       (int)(NT / 4), 3);
  cast_multi<<<1024, 256, 0, stream>>>(Wq, Wk, Wv, Wo, Wqb, Wkb, Wvb, Wob,
                                       (int)(NW / 4), 4);
  qkv_proj<<<dim3(48, 32), 256, 0, stream>>>(qb, kb, vb, Wqb, Wkb, Wvb, Qh, Kh, Vt);
  attn_fwd<<<dim3(32, 16, 2), 256, 0, stream>>>(Qh, Kh, Vt, mask, Oh);
  gemm_o<<<dim3(16, 32), 256, 0, stream>>>(Oh, Wob, out);
}

// Round 3
// 296.085 us; speedup vs baseline: 1.3419x; 1.3419x over previous
//
#include <hip/hip_runtime.h>
#include <hip/hip_bf16.h>
#include <stdint.h>

using bf16 = __hip_bfloat16;
typedef __attribute__((ext_vector_type(8))) short short8;     // 8 bf16 MFMA frag
typedef __attribute__((ext_vector_type(4))) float f32x4;      // MFMA acc
typedef __attribute__((ext_vector_type(4))) float float4v;
typedef __attribute__((ext_vector_type(4))) unsigned short us4;

#define LDS_U32 __attribute__((address_space(3))) uint32_t
#define GLB_U32 __attribute__((address_space(1))) uint32_t

__device__ __forceinline__ unsigned short f2b(float f) {
  union { float f; uint32_t u; } x; x.f = f;
  uint32_t r = x.u + 0x7FFFu + ((x.u >> 16) & 1u);  // RNE
  return (unsigned short)(r >> 16);
}

// ---------------- fp32 -> bf16 cast, up to 4 arrays in one launch ----------------
__global__ void cast_multi(const float* __restrict__ s0, const float* __restrict__ s1,
                           const float* __restrict__ s2, const float* __restrict__ s3,
                           bf16* __restrict__ d0, bf16* __restrict__ d1,
                           bf16* __restrict__ d2, bf16* __restrict__ d3,
                           int nvec, int narr) {
  int total = nvec * narr;
  for (int i = blockIdx.x * blockDim.x + threadIdx.x; i < total;
       i += gridDim.x * blockDim.x) {
    int a = i / nvec, vi = i - a * nvec;
    const float* s = (a == 0) ? s0 : (a == 1) ? s1 : (a == 2) ? s2 : s3;
    bf16* d = (a == 0) ? d0 : (a == 1) ? d1 : (a == 2) ? d2 : d3;
    float4v x = ((const float4v*)s)[vi];
    us4 y;
    y.x = f2b(x.x); y.y = f2b(x.y); y.z = f2b(x.z); y.w = f2b(x.w);
    ((us4*)d)[vi] = y;
  }
}

// ---------------- fused QKV projection: 128x64 tiles, bf16 in, fp32 acc ----------------
__global__ __launch_bounds__(256, 2)
void qkv_proj(const bf16* __restrict__ Aq, const bf16* __restrict__ Ak,
              const bf16* __restrict__ Av,
              const bf16* __restrict__ Wq, const bf16* __restrict__ Wk,
              const bf16* __restrict__ Wv,
              bf16* __restrict__ Qh, bf16* __restrict__ Kh, bf16* __restrict__ Vt) {
  __shared__ bf16 Alds[128 * 64];
  __shared__ bf16 Blds[64 * 64];
  const int t = threadIdx.x, lane = t & 63, wave = t >> 6;
  const int l15 = lane & 15, l4 = lane >> 4;
  const int seg = blockIdx.x >> 4;
  const int n0 = (blockIdx.x & 15) * 64;
  const int m0 = blockIdx.y * 128;
  const bf16* A = (seg == 0) ? Aq : (seg == 1) ? Ak : Av;
  const bf16* B = (seg == 0) ? Wq : (seg == 1) ? Wk : Wv;
  const int K = 1024;
  const int wr = (wave >> 1) * 64, wc = (wave & 1) * 32;

  f32x4 acc[4][2] = {};

  for (int kt = 0; kt < K; kt += 64) {
#pragma unroll
    for (int i = 0; i < 4; ++i) {
      int f = i * 256 + t, row = f >> 3, csrc = (f & 7) ^ (row & 7);
      __builtin_amdgcn_global_load_lds(
          (const GLB_U32*)(A + (size_t)(m0 + row) * K + kt + csrc * 8),
          (LDS_U32*)(Alds + f * 8), 16, 0, 0);
    }
#pragma unroll
    for (int i = 0; i < 2; ++i) {
      int f = i * 256 + t, row = f >> 3, csrc = (f & 7) ^ (row & 7);
      __builtin_amdgcn_global_load_lds(
          (const GLB_U32*)(B + (size_t)(n0 + row) * K + kt + csrc * 8),
          (LDS_U32*)(Blds + f * 8), 16, 0, 0);
    }
    __syncthreads();
#pragma unroll
    for (int ks = 0; ks < 2; ++ks) {
      short8 af[4], bfr[2];
#pragma unroll
      for (int mi = 0; mi < 4; ++mi) {
        int row = wr + mi * 16 + l15;
        int ch = (ks * 4 + l4) ^ (row & 7);
        af[mi] = *(const short8*)(Alds + row * 64 + ch * 8);
      }
#pragma unroll
      for (int ni = 0; ni < 2; ++ni) {
        int row = wc + ni * 16 + l15;
        int ch = (ks * 4 + l4) ^ (row & 7);
        bfr[ni] = *(const short8*)(Blds + row * 64 + ch * 8);
      }
#pragma unroll
      for (int mi = 0; mi < 4; ++mi)
#pragma unroll
        for (int ni = 0; ni < 2; ++ni)
          acc[mi][ni] = __builtin_amdgcn_mfma_f32_16x16x32_bf16(
              af[mi], bfr[ni], acc[mi][ni], 0, 0, 0);
    }
    __syncthreads();
  }

#pragma unroll
  for (int mi = 0; mi < 4; ++mi) {
#pragma unroll
    for (int ni = 0; ni < 2; ++ni) {
      int rbase = m0 + wr + mi * 16 + l4 * 4;
      int col = n0 + wc + ni * 16 + l15;
      if (seg < 2) {
        unsigned short* C = (unsigned short*)((seg == 0) ? Qh : Kh);
#pragma unroll
        for (int r = 0; r < 4; ++r)
          C[(size_t)(rbase + r) * 1024 + col] = f2b(acc[mi][ni][r]);
      } else {
        unsigned short* C = (unsigned short*)Vt;
        int bb = rbase >> 11, s = rbase & 2047;
        size_t addr = ((size_t)(bb * 1024 + col)) * 2048 + s;
        us4 y;
        y.x = f2b(acc[mi][ni][0]); y.y = f2b(acc[mi][ni][1]);
        y.z = f2b(acc[mi][ni][2]); y.w = f2b(acc[mi][ni][3]);
        *(us4*)(C + addr) = y;
      }
    }
  }
}

// ---------------- output projection: fp32 out, 128x64 tiles ----------------
__global__ __launch_bounds__(256, 2)
void gemm_o(const bf16* __restrict__ A, const bf16* __restrict__ B,
            float* __restrict__ C) {
  __shared__ bf16 Alds[128 * 64];
  __shared__ bf16 Blds[64 * 64];
  const int t = threadIdx.x, lane = t & 63, wave = t >> 6;
  const int l15 = lane & 15, l4 = lane >> 4;
  const int n0 = blockIdx.x * 64, m0 = blockIdx.y * 128;
  const int K = 1024;
  const int wr = (wave >> 1) * 64, wc = (wave & 1) * 32;

  f32x4 acc[4][2] = {};

  for (int kt = 0; kt < K; kt += 64) {
#pragma unroll
    for (int i = 0; i < 4; ++i) {
      int f = i * 256 + t, row = f >> 3, csrc = (f & 7) ^ (row & 7);
      __builtin_amdgcn_global_load_lds(
          (const GLB_U32*)(A + (size_t)(m0 + row) * K + kt + csrc * 8),
          (LDS_U32*)(Alds + f * 8), 16, 0, 0);
    }
#pragma unroll
    for (int i = 0; i < 2; ++i) {
      int f = i * 256 + t, row = f >> 3, csrc = (f & 7) ^ (row & 7);
      __builtin_amdgcn_global_load_lds(
          (const GLB_U32*)(B + (size_t)(n0 + row) * K + kt + csrc * 8),
          (LDS_U32*)(Blds + f * 8), 16, 0, 0);
    }
    __syncthreads();
#pragma unroll
    for (int ks = 0; ks < 2; ++ks) {
      short8 af[4], bfr[2];
#pragma unroll
      for (int mi = 0; mi < 4; ++mi) {
        int row = wr + mi * 16 + l15;
        int ch = (ks * 4 + l4) ^ (row & 7);
        af[mi] = *(const short8*)(Alds + row * 64 + ch * 8);
      }
#pragma unroll
      for (int ni = 0; ni < 2; ++ni) {
        int row = wc + ni * 16 + l15;
        int ch = (ks * 4 + l4) ^ (row & 7);
        bfr[ni] = *(const short8*)(Blds + row * 64 + ch * 8);
      }
#pragma unroll
      for (int mi = 0; mi < 4; ++mi)
#pragma unroll
        for (int ni = 0; ni < 2; ++ni)
          acc[mi][ni] = __builtin_amdgcn_mfma_f32_16x16x32_bf16(
              af[mi], bfr[ni], acc[mi][ni], 0, 0, 0);
    }
    __syncthreads();
  }

#pragma unroll
  for (int mi = 0; mi < 4; ++mi)
#pragma unroll
    for (int ni = 0; ni < 2; ++ni) {
      int rbase = m0 + wr + mi * 16 + l4 * 4;
      int col = n0 + wc + ni * 16 + l15;
#pragma unroll
      for (int r = 0; r < 4; ++r)
        C[(size_t)(rbase + r) * 1024 + col] = acc[mi][ni][r];
    }
}

// ---------------- causal flash attention, LDS-staged K/V ----------------
// Block x handles strips {x, 31-x} (64 q-rows each): waves 0,1 -> strip x,
// waves 2,3 -> strip 31-x; 32 q-rows per wave. K/V tiles (64 keys) staged in
// LDS via async global_load_lds, double-buffered, shared by all 4 waves.
__global__ __launch_bounds__(256, 2)
void attn_fwd(const bf16* __restrict__ Q, const bf16* __restrict__ K,
              const bf16* __restrict__ Vt, const int* __restrict__ mask,
              bf16* __restrict__ O) {
  const int b = blockIdx.z, h = blockIdx.y, x = blockIdx.x;
  const int t = threadIdx.x, wave = t >> 6, lane = t & 63;
  const int l15 = lane & 15, l4 = lane >> 4;
  const int strip = (wave < 2) ? x : (31 - x);
  const int q0 = strip * 64 + (wave & 1) * 32;
  const int myTiles = strip + 1;   // this wave computes tiles 0..strip
  const int NT = 32 - x;           // tiles the block stages

  __shared__ bf16 Klds[2][64 * 64];
  __shared__ bf16 Vlds[2][64 * 64];
  __shared__ float biasLds[2048];
  __shared__ bf16 PldsAll[4][32 * 72];
  bf16* Plds = PldsAll[wave];

  for (int i = t; i < 2048; i += 256)
    biasLds[i] = mask[b * 2048 + i] ? 0.f : -1e9f;

  const size_t bqk = (size_t)b * 2048 * 1024 + h * 64;
  const size_t vbase = (size_t)(b * 16 + h) * 64 * 2048;
  const float SCL = 0.18033688f;  // 1/sqrt(64) * log2(e)

#define STAGE(TT, BB)                                                          \
  {                                                                            \
    _Pragma("unroll") for (int i_ = 0; i_ < 2; ++i_) {                         \
      int f_ = i_ * 256 + t, row_ = f_ >> 3, cs_ = (f_ & 7) ^ (row_ & 7);      \
      __builtin_amdgcn_global_load_lds(                                        \
          (const GLB_U32*)(K + bqk + (size_t)((TT) * 64 + row_) * 1024 +       \
                           cs_ * 8),                                           \
          (LDS_U32*)(Klds[BB] + f_ * 8), 16, 0, 0);                            \
      __builtin_amdgcn_global_load_lds(                                        \
          (const GLB_U32*)(Vt + vbase + (size_t)row_ * 2048 + (TT) * 64 +      \
                           cs_ * 8),                                           \
          (LDS_U32*)(Vlds[BB] + f_ * 8), 16, 0, 0);                            \
    }                                                                          \
  }

  short8 qa[2][2];
#pragma unroll
  for (int qm = 0; qm < 2; ++qm)
#pragma unroll
    for (int ks = 0; ks < 2; ++ks)
      qa[qm][ks] = *(const short8*)(Q + bqk + (size_t)(q0 + qm * 16 + l15) * 1024 +
                                    ks * 32 + l4 * 8);

  f32x4 acc[2][4] = {};
  float mrun[2][4], lrun[2][4];
#pragma unroll
  for (int qm = 0; qm < 2; ++qm)
#pragma unroll
    for (int r = 0; r < 4; ++r) { mrun[qm][r] = -1e30f; lrun[qm][r] = 0.f; }

  STAGE(0, 0);
  __syncthreads();

  int cur = 0;
  for (int tt = 0; tt < NT; ++tt) {
    if (tt + 1 < NT) STAGE(tt + 1, cur ^ 1);

    if (tt < myTiles) {
      short8 kb[4][2];
#pragma unroll
      for (int kn = 0; kn < 4; ++kn)
#pragma unroll
        for (int ks = 0; ks < 2; ++ks) {
          int row = kn * 16 + l15;
          int ch = (ks * 4 + l4) ^ (row & 7);
          kb[kn][ks] = *(const short8*)(Klds[cur] + row * 64 + ch * 8);
        }

      f32x4 sc[2][4] = {};
#pragma unroll
      for (int ks = 0; ks < 2; ++ks)
#pragma unroll
        for (int qm = 0; qm < 2; ++qm)
#pragma unroll
          for (int kn = 0; kn < 4; ++kn)
            sc[qm][kn] = __builtin_amdgcn_mfma_f32_16x16x32_bf16(
                qa[qm][ks], kb[kn][ks], sc[qm][kn], 0, 0, 0);

      float bofs[4];
#pragma unroll
      for (int kn = 0; kn < 4; ++kn) bofs[kn] = biasLds[tt * 64 + kn * 16 + l15];

      if (tt == strip) {  // diagonal tile: causal compare
#pragma unroll
        for (int qm = 0; qm < 2; ++qm)
#pragma unroll
          for (int kn = 0; kn < 4; ++kn) {
            int kg = tt * 64 + kn * 16 + l15;
#pragma unroll
            for (int r = 0; r < 4; ++r) {
              int qg = q0 + qm * 16 + l4 * 4 + r;
              sc[qm][kn][r] = (kg > qg) ? -1e9f : sc[qm][kn][r] * SCL + bofs[kn];
            }
          }
      } else {
#pragma unroll
        for (int qm = 0; qm < 2; ++qm)
#pragma unroll
          for (int kn = 0; kn < 4; ++kn)
#pragma unroll
            for (int r = 0; r < 4; ++r)
              sc[qm][kn][r] = sc[qm][kn][r] * SCL + bofs[kn];
      }

#pragma unroll
      for (int qm = 0; qm < 2; ++qm)
#pragma unroll
        for (int r = 0; r < 4; ++r) {
          float mx = fmaxf(fmaxf(sc[qm][0][r], sc[qm][1][r]),
                           fmaxf(sc[qm][2][r], sc[qm][3][r]));
          mx = fmaxf(mx, __shfl_xor(mx, 1));
          mx = fmaxf(mx, __shfl_xor(mx, 2));
          mx = fmaxf(mx, __shfl_xor(mx, 4));
          mx = fmaxf(mx, __shfl_xor(mx, 8));
          float mnew = fmaxf(mrun[qm][r], mx);
          float corr = exp2f(mrun[qm][r] - mnew);
          mrun[qm][r] = mnew;
          float rs = 0.f;
#pragma unroll
          for (int kn = 0; kn < 4; ++kn) {
            float p = exp2f(sc[qm][kn][r] - mnew);
            sc[qm][kn][r] = p;
            rs += p;
          }
          rs += __shfl_xor(rs, 1);
          rs += __shfl_xor(rs, 2);
          rs += __shfl_xor(rs, 4);
          rs += __shfl_xor(rs, 8);
          lrun[qm][r] = lrun[qm][r] * corr + rs;
#pragma unroll
          for (int nd = 0; nd < 4; ++nd) acc[qm][nd][r] *= corr;
        }

#pragma unroll
      for (int qm = 0; qm < 2; ++qm)
#pragma unroll
        for (int kn = 0; kn < 4; ++kn)
#pragma unroll
          for (int r = 0; r < 4; ++r)
            ((unsigned short*)Plds)[(qm * 16 + l4 * 4 + r) * 72 + kn * 16 + l15] =
                f2b(sc[qm][kn][r]);

#pragma unroll
      for (int ks = 0; ks < 2; ++ks) {
        short8 pa[2], vbf[4];
#pragma unroll
        for (int qm = 0; qm < 2; ++qm)
          pa[qm] = *(const short8*)(Plds + (qm * 16 + l15) * 72 + ks * 32 + l4 * 8);
#pragma unroll
        for (int nd = 0; nd < 4; ++nd) {
          int row = nd * 16 + l15;
          int ch = (ks * 4 + l4) ^ (row & 7);
          vbf[nd] = *(const short8*)(Vlds[cur] + row * 64 + ch * 8);
        }
#pragma unroll
        for (int qm = 0; qm < 2; ++qm)
#pragma unroll
          for (int nd = 0; nd < 4; ++nd)
            acc[qm][nd] = __builtin_amdgcn_mfma_f32_16x16x32_bf16(
                pa[qm], vbf[nd], acc[qm][nd], 0, 0, 0);
      }
    }

    __syncthreads();  // drains DMA (vmcnt) + joins readers before overwrite
    cur ^= 1;
  }

  float invr[2][4];
#pragma unroll
  for (int qm = 0; qm < 2; ++qm)
#pragma unroll
    for (int r = 0; r < 4; ++r) invr[qm][r] = 1.0f / lrun[qm][r];

#pragma unroll
  for (int qm = 0; qm < 2; ++qm)
#pragma unroll
    for (int nd = 0; nd < 4; ++nd)
#pragma unroll
      for (int r = 0; r < 4; ++r)
        ((unsigned short*)O)[bqk + (size_t)(q0 + qm * 16 + l4 * 4 + r) * 1024 +
                             nd * 16 + l15] = f2b(acc[qm][nd][r] * invr[qm][r]);
#undef STAGE
}

// ---------------- launch ----------------
extern "C" void kernel_launch(void* const* d_in, const int* in_sizes, int n_in,
                              void* d_out, int out_size, void* d_ws, size_t ws_size,
                              hipStream_t stream) {
  const float* q = (const float*)d_in[0];
  const float* k = (const float*)d_in[1];
  const float* v = (const float*)d_in[2];
  const int* mask = (const int*)d_in[3];
  const float* Wq = (const float*)d_in[4];
  const float* Wk = (const float*)d_in[5];
  const float* Wv = (const float*)d_in[6];
  const float* Wo = (const float*)d_in[7];
  float* out = (float*)d_out;

  const size_t NT = 4096 * 1024;
  const size_t NW = 1024 * 1024;
  bf16* p = (bf16*)d_ws;
  bf16* qb = p;  p += NT;
  bf16* kb = p;  p += NT;
  bf16* vb = p;  p += NT;
  bf16* Wqb = p; p += NW;
  bf16* Wkb = p; p += NW;
  bf16* Wvb = p; p += NW;
  bf16* Wob = p; p += NW;
  bf16* Qh = p;  p += NT;
  bf16* Kh = p;  p += NT;
  bf16* Vt = p;  p += NT;
  bf16* Oh = p;  p += NT;

  cast_multi<<<2048, 256, 0, stream>>>(q, k, v, nullptr, qb, kb, vb, nullptr,
                                       (int)(NT / 4), 3);
  cast_multi<<<1024, 256, 0, stream>>>(Wq, Wk, Wv, Wo, Wqb, Wkb, Wvb, Wob,
                                       (int)(NW / 4), 4);
  qkv_proj<<<dim3(48, 32), 256, 0, stream>>>(qb, kb, vb, Wqb, Wkb, Wvb, Qh, Kh, Vt);
  attn_fwd<<<dim3(16, 16, 2), 256, 0, stream>>>(Qh, Kh, Vt, mask, Oh);
  gemm_o<<<dim3(16, 32), 256, 0, stream>>>(Oh, Wob, out);
}

// Round 4
// 233.234 us; speedup vs baseline: 1.7035x; 1.2695x over previous
//
#include <hip/hip_runtime.h>
#include <hip/hip_bf16.h>
#include <stdint.h>

using bf16 = __hip_bfloat16;
typedef __attribute__((ext_vector_type(8))) short short8;      // 8 bf16 MFMA frag
typedef __attribute__((ext_vector_type(4))) float f32x4;
typedef __attribute__((ext_vector_type(16))) float f32x16;
typedef __attribute__((ext_vector_type(4))) float float4v;
typedef __attribute__((ext_vector_type(4))) unsigned short us4;
typedef __attribute__((ext_vector_type(4))) uint32_t u32x4;

#define LDS_U32 __attribute__((address_space(3))) uint32_t
#define GLB_U32 __attribute__((address_space(1))) uint32_t

__device__ __forceinline__ unsigned short f2b(float f) {
  union { float f; uint32_t u; } x; x.f = f;
  uint32_t r = x.u + 0x7FFFu + ((x.u >> 16) & 1u);  // RNE
  return (unsigned short)(r >> 16);
}

// ---------------- fp32 -> bf16 cast ----------------
__global__ void cast_multi(const float* __restrict__ s0, const float* __restrict__ s1,
                           const float* __restrict__ s2, const float* __restrict__ s3,
                           bf16* __restrict__ d0, bf16* __restrict__ d1,
                           bf16* __restrict__ d2, bf16* __restrict__ d3,
                           int nvec, int narr) {
  int total = nvec * narr;
  for (int i = blockIdx.x * blockDim.x + threadIdx.x; i < total;
       i += gridDim.x * blockDim.x) {
    int a = i / nvec, vi = i - a * nvec;
    const float* s = (a == 0) ? s0 : (a == 1) ? s1 : (a == 2) ? s2 : s3;
    bf16* d = (a == 0) ? d0 : (a == 1) ? d1 : (a == 2) ? d2 : d3;
    float4v x = ((const float4v*)s)[vi];
    us4 y;
    y.x = f2b(x.x); y.y = f2b(x.y); y.z = f2b(x.z); y.w = f2b(x.w);
    ((us4*)d)[vi] = y;
  }
}

// ---------------- fused QKV projection: 128x128 tiles (m97 geometry) ----------------
// seg 0: Qh = qb@Wq^T; seg 1: Kh = kb@Wk^T; seg 2: Vt[(b*1024+col)][2048] transposed.
__global__ __launch_bounds__(256, 2)
void qkv_proj(const bf16* __restrict__ Aq, const bf16* __restrict__ Ak,
              const bf16* __restrict__ Av,
              const bf16* __restrict__ Wq, const bf16* __restrict__ Wk,
              const bf16* __restrict__ Wv,
              bf16* __restrict__ Qh, bf16* __restrict__ Kh, bf16* __restrict__ Vt) {
  __shared__ bf16 Alds[128 * 64];
  __shared__ bf16 Blds[128 * 64];
  const int t = threadIdx.x, lane = t & 63, wave = t >> 6;
  const int l15 = lane & 15, l4 = lane >> 4;
  const int seg = blockIdx.x >> 3;
  const int n0 = (blockIdx.x & 7) * 128;
  const int m0 = blockIdx.y * 128;
  const bf16* A = (seg == 0) ? Aq : (seg == 1) ? Ak : Av;
  const bf16* B = (seg == 0) ? Wq : (seg == 1) ? Wk : Wv;
  const int K = 1024;
  const int wr = (wave >> 1) * 64, wc = (wave & 1) * 64;

  f32x4 acc[4][4] = {};

  for (int kt = 0; kt < K; kt += 64) {
#pragma unroll
    for (int i = 0; i < 4; ++i) {
      int f = i * 256 + t, row = f >> 3, csrc = (f & 7) ^ (row & 7);
      __builtin_amdgcn_global_load_lds(
          (const GLB_U32*)(A + (size_t)(m0 + row) * K + kt + csrc * 8),
          (LDS_U32*)(Alds + f * 8), 16, 0, 0);
      __builtin_amdgcn_global_load_lds(
          (const GLB_U32*)(B + (size_t)(n0 + row) * K + kt + csrc * 8),
          (LDS_U32*)(Blds + f * 8), 16, 0, 0);
    }
    __syncthreads();
#pragma unroll
    for (int ks = 0; ks < 2; ++ks) {
      short8 af[4], bfr[4];
#pragma unroll
      for (int mi = 0; mi < 4; ++mi) {
        int row = wr + mi * 16 + l15;
        int ch = (ks * 4 + l4) ^ (row & 7);
        af[mi] = *(const short8*)(Alds + row * 64 + ch * 8);
      }
#pragma unroll
      for (int ni = 0; ni < 4; ++ni) {
        int row = wc + ni * 16 + l15;
        int ch = (ks * 4 + l4) ^ (row & 7);
        bfr[ni] = *(const short8*)(Blds + row * 64 + ch * 8);
      }
#pragma unroll
      for (int mi = 0; mi < 4; ++mi)
#pragma unroll
        for (int ni = 0; ni < 4; ++ni)
          acc[mi][ni] = __builtin_amdgcn_mfma_f32_16x16x32_bf16(
              af[mi], bfr[ni], acc[mi][ni], 0, 0, 0);
    }
    __syncthreads();
  }

#pragma unroll
  for (int mi = 0; mi < 4; ++mi) {
#pragma unroll
    for (int ni = 0; ni < 4; ++ni) {
      int rbase = m0 + wr + mi * 16 + l4 * 4;
      int col = n0 + wc + ni * 16 + l15;
      if (seg < 2) {
        unsigned short* C = (unsigned short*)((seg == 0) ? Qh : Kh);
#pragma unroll
        for (int r = 0; r < 4; ++r)
          C[(size_t)(rbase + r) * 1024 + col] = f2b(acc[mi][ni][r]);
      } else {
        unsigned short* C = (unsigned short*)Vt;
        int bb = rbase >> 11, sidx = rbase & 2047;
        size_t addr = ((size_t)(bb * 1024 + col)) * 2048 + sidx;
        us4 y;
        y.x = f2b(acc[mi][ni][0]); y.y = f2b(acc[mi][ni][1]);
        y.z = f2b(acc[mi][ni][2]); y.w = f2b(acc[mi][ni][3]);
        *(us4*)(C + addr) = y;
      }
    }
  }
}

// ---------------- output projection: fp32 out, 128x64 tiles ----------------
__global__ __launch_bounds__(256, 2)
void gemm_o(const bf16* __restrict__ A, const bf16* __restrict__ B,
            float* __restrict__ C) {
  __shared__ bf16 Alds[128 * 64];
  __shared__ bf16 Blds[64 * 64];
  const int t = threadIdx.x, lane = t & 63, wave = t >> 6;
  const int l15 = lane & 15, l4 = lane >> 4;
  const int n0 = blockIdx.x * 64, m0 = blockIdx.y * 128;
  const int K = 1024;
  const int wr = (wave >> 1) * 64, wc = (wave & 1) * 32;

  f32x4 acc[4][2] = {};

  for (int kt = 0; kt < K; kt += 64) {
#pragma unroll
    for (int i = 0; i < 4; ++i) {
      int f = i * 256 + t, row = f >> 3, csrc = (f & 7) ^ (row & 7);
      __builtin_amdgcn_global_load_lds(
          (const GLB_U32*)(A + (size_t)(m0 + row) * K + kt + csrc * 8),
          (LDS_U32*)(Alds + f * 8), 16, 0, 0);
    }
#pragma unroll
    for (int i = 0; i < 2; ++i) {
      int f = i * 256 + t, row = f >> 3, csrc = (f & 7) ^ (row & 7);
      __builtin_amdgcn_global_load_lds(
          (const GLB_U32*)(B + (size_t)(n0 + row) * K + kt + csrc * 8),
          (LDS_U32*)(Blds + f * 8), 16, 0, 0);
    }
    __syncthreads();
#pragma unroll
    for (int ks = 0; ks < 2; ++ks) {
      short8 af[4], bfr[2];
#pragma unroll
      for (int mi = 0; mi < 4; ++mi) {
        int row = wr + mi * 16 + l15;
        int ch = (ks * 4 + l4) ^ (row & 7);
        af[mi] = *(const short8*)(Alds + row * 64 + ch * 8);
      }
#pragma unroll
      for (int ni = 0; ni < 2; ++ni) {
        int row = wc + ni * 16 + l15;
        int ch = (ks * 4 + l4) ^ (row & 7);
        bfr[ni] = *(const short8*)(Blds + row * 64 + ch * 8);
      }
#pragma unroll
      for (int mi = 0; mi < 4; ++mi)
#pragma unroll
        for (int ni = 0; ni < 2; ++ni)
          acc[mi][ni] = __builtin_amdgcn_mfma_f32_16x16x32_bf16(
              af[mi], bfr[ni], acc[mi][ni], 0, 0, 0);
    }
    __syncthreads();
  }

#pragma unroll
  for (int mi = 0; mi < 4; ++mi)
#pragma unroll
    for (int ni = 0; ni < 2; ++ni) {
      int rbase = m0 + wr + mi * 16 + l4 * 4;
      int col = n0 + wc + ni * 16 + l15;
#pragma unroll
      for (int r = 0; r < 4; ++r)
        C[(size_t)(rbase + r) * 1024 + col] = acc[mi][ni][r];
    }
}

// ---------------- causal flash attention: swapped QK^T, in-register softmax ----------------
// 32x32x16 MFMA. Wave = one k-half of strip pair (j, 63-j), 32 q-rows/strip.
// scT[u] lane: P^T[k=32u+crow(p,hi)][q=l31], crow = (p&3)+8(p>>2)+4hi.
// Split-K merge between wave pairs via LDS. No barriers in main loop.
__global__ __launch_bounds__(256, 2)
void attn_fwd(const bf16* __restrict__ Q, const bf16* __restrict__ K,
              const bf16* __restrict__ Vt, const int* __restrict__ mask,
              bf16* __restrict__ O) {
  const int lin = blockIdx.x;
  const int xcd = lin & 7, q8 = lin >> 3;
  const int bh = xcd + 8 * (q8 & 3), g = q8 >> 2;   // same head -> same XCD (L2)
  const int b = bh >> 4, h = bh & 15;
  const int wave = threadIdx.x >> 6, lane = threadIdx.x & 63;
  const int l31 = lane & 31, hi = lane >> 5;
  const int job = 2 * g + (wave >> 1);              // 0..31
  const int halfk = wave & 1, wp = wave >> 1;

  __shared__ float accL[2][64][33];  // split-K merge buffer (+1 pad: conflict-free)
  __shared__ float mlL[2][64][2];

  const size_t bqk = (size_t)b * 2048 * 1024 + h * 64;
  const size_t vbase = ((size_t)b * 1024 + h * 64) * 2048;
  const float SCLE = 0.18033688011112042f;  // (1/sqrt(64))*log2(e)

  for (int si = 0; si < 2; ++si) {
    const int s = si ? (63 - job) : job;   // strip: 32 q-rows
    const int q0 = 32 * s;
    const int T = (s >> 1) + 1;            // KV tiles of 64 this strip needs
    const int hsplit = (T + 1) >> 1;
    const int tstart = halfk ? hsplit : 0;
    const int tend = halfk ? T : hsplit;

    short8 qf[4];
#pragma unroll
    for (int s4 = 0; s4 < 4; ++s4)
      qf[s4] = *(const short8*)(Q + bqk + (size_t)(q0 + l31) * 1024 + 16 * s4 + 8 * hi);

    f32x16 acc0 = {}, acc1 = {};
    float m = -1e30f, l = 0.f;

    short8 kf[2][4], kn[2][4], vf[2][4];
    if (tstart < tend) {
#pragma unroll
      for (int u = 0; u < 2; ++u)
#pragma unroll
        for (int s4 = 0; s4 < 4; ++s4)
          kf[u][s4] = *(const short8*)(K + bqk +
              (size_t)(tstart * 64 + 32 * u + l31) * 1024 + 16 * s4 + 8 * hi);
    }

    for (int tt = tstart; tt < tend; ++tt) {
      // V loads issued early, consumed after softmax
#pragma unroll
      for (int n = 0; n < 2; ++n)
#pragma unroll
        for (int t = 0; t < 4; ++t)
          vf[n][t] = *(const short8*)(Vt + vbase + (size_t)(32 * n + l31) * 2048 +
                                      tt * 64 + 16 * t + 8 * hi);
      int mv = mask[b * 2048 + tt * 64 + lane];

      f32x16 s0 = {}, s1 = {};
#pragma unroll
      for (int s4 = 0; s4 < 4; ++s4) {
        s0 = __builtin_amdgcn_mfma_f32_32x32x16_bf16(kf[0][s4], qf[s4], s0, 0, 0, 0);
        s1 = __builtin_amdgcn_mfma_f32_32x32x16_bf16(kf[1][s4], qf[s4], s1, 0, 0, 0);
      }
      if (tt + 1 < tend) {  // K prefetch for next tile
#pragma unroll
        for (int u = 0; u < 2; ++u)
#pragma unroll
          for (int s4 = 0; s4 < 4; ++s4)
            kn[u][s4] = *(const short8*)(K + bqk +
                (size_t)((tt + 1) * 64 + 32 * u + l31) * 1024 + 16 * s4 + 8 * hi);
      }

      float w[2][16];
#pragma unroll
      for (int p = 0; p < 16; ++p) { w[0][p] = s0[p] * SCLE; w[1][p] = s1[p] * SCLE; }

      uint64_t bits = __ballot(mv != 0);
      if (bits != ~0ull) {  // pad-mask (rare; uniform branch)
        uint64_t bs = bits >> (4 * hi);
#pragma unroll
        for (int u = 0; u < 2; ++u)
#pragma unroll
          for (int p = 0; p < 16; ++p)
            if (!((bs >> (32 * u + (p & 3) + 8 * (p >> 2))) & 1)) w[u][p] = -3e38f;
      }
      if (tt == T - 1) {  // causal clamp, diagonal tile only
        int qr = 32 * (s & 1) + l31 - 4 * hi;
#pragma unroll
        for (int u = 0; u < 2; ++u)
#pragma unroll
          for (int p = 0; p < 16; ++p)
            if (32 * u + (p & 3) + 8 * (p >> 2) > qr) w[u][p] = -3e38f;
      }

      // tile max: in-register tree + one cross-half swap
      float tm = fmaxf(w[0][0], w[1][0]);
#pragma unroll
      for (int p = 1; p < 16; ++p) tm = fmaxf(tm, fmaxf(w[0][p], w[1][p]));
      tm = fmaxf(tm, __shfl_xor(tm, 32));

      // defer-max (T13): rescale only when max grows past threshold
      if (!__all(tm <= m + 8.f)) {
        float mn = fmaxf(m, tm);
        float corr = __builtin_amdgcn_exp2f(m - mn);
        m = mn; l *= corr;
#pragma unroll
        for (int p = 0; p < 16; ++p) {
          float ct = __shfl(corr, (p & 3) + 8 * (p >> 2) + 4 * hi);
          acc0[p] *= ct; acc1[p] *= ct;
        }
      }

      float ts = 0.f;
#pragma unroll
      for (int u = 0; u < 2; ++u)
#pragma unroll
        for (int p = 0; p < 16; ++p) {
          float pv = __builtin_amdgcn_exp2f(w[u][p] - m);
          w[u][p] = pv; ts += pv;
        }
      ts += __shfl_xor(ts, 32);
      l += ts;

      // pack P to bf16 pairs (T12): 16 cvt_pk
      uint32_t pkk[2][8];
#pragma unroll
      for (int u = 0; u < 2; ++u)
#pragma unroll
        for (int a = 0; a < 4; ++a)
#pragma unroll
          for (int w2 = 0; w2 < 2; ++w2) {
            uint32_t r;
            asm("v_cvt_pk_bf16_f32 %0, %1, %2"
                : "=v"(r) : "v"(w[u][4 * a + 2 * w2]), "v"(w[u][4 * a + 2 * w2 + 1]));
            pkk[u][2 * a + w2] = r;
          }

      // build PV A-frags: half-swap + select, then 8 PV MFMAs
#pragma unroll
      for (int t = 0; t < 4; ++t) {
        const int u = t >> 1, alo = 2 * (t & 1);
        uint32_t wd[4];
#pragma unroll
        for (int w2 = 0; w2 < 2; ++w2) {
          uint32_t own_lo = pkk[u][2 * alo + w2];
          uint32_t own_hi = pkk[u][2 * alo + 2 + w2];
          uint32_t pre = hi ? own_lo : own_hi;
          uint32_t sx = (uint32_t)__shfl_xor((int)pre, 32);
          wd[w2] = hi ? sx : own_lo;
          wd[2 + w2] = hi ? own_hi : sx;
        }
        u32x4 wv = {wd[0], wd[1], wd[2], wd[3]};
        short8 paf = __builtin_bit_cast(short8, wv);
        acc0 = __builtin_amdgcn_mfma_f32_32x32x16_bf16(paf, vf[0][t], acc0, 0, 0, 0);
        acc1 = __builtin_amdgcn_mfma_f32_32x32x16_bf16(paf, vf[1][t], acc1, 0, 0, 0);
      }

#pragma unroll
      for (int u = 0; u < 2; ++u)
#pragma unroll
        for (int s4 = 0; s4 < 4; ++s4) kf[u][s4] = kn[u][s4];
    }

    // ---- split-K merge: odd wave publishes, even wave combines + writes ----
    if (halfk) {
#pragma unroll
      for (int p = 0; p < 16; ++p) {
        accL[wp][lane][p] = acc0[p];
        accL[wp][lane][16 + p] = acc1[p];
      }
      mlL[wp][lane][0] = m; mlL[wp][lane][1] = l;
    }
    __syncthreads();
    if (!halfk) {
      float mB = mlL[wp][lane][0], lB = mlL[wp][lane][1];
      float ms = fmaxf(m, mB);
      float cAr = __builtin_amdgcn_exp2f(m - ms);
      float cBr = __builtin_amdgcn_exp2f(mB - ms);
      float inv = 1.f / (cAr * l + cBr * lB);
      float fa = cAr * inv, fb = cBr * inv;
      unsigned short* Ou = (unsigned short*)O;
#pragma unroll
      for (int p = 0; p < 16; ++p) {
        int crow = (p & 3) + 8 * (p >> 2) + 4 * hi;
        float faT = __shfl(fa, crow);
        float fbT = __shfl(fb, crow);
        float o0 = acc0[p] * faT + accL[wp][lane][p] * fbT;
        float o1 = acc1[p] * faT + accL[wp][lane][16 + p] * fbT;
        size_t ro = (size_t)(b * 2048 + q0 + crow) * 1024 + h * 64;
        Ou[ro + l31] = f2b(o0);
        Ou[ro + 32 + l31] = f2b(o1);
      }
    }
    __syncthreads();
  }
}

// ---------------- launch ----------------
extern "C" void kernel_launch(void* const* d_in, const int* in_sizes, int n_in,
                              void* d_out, int out_size, void* d_ws, size_t ws_size,
                              hipStream_t stream) {
  const float* q = (const float*)d_in[0];
  const float* k = (const float*)d_in[1];
  const float* v = (const float*)d_in[2];
  const int* mask = (const int*)d_in[3];
  const float* Wq = (const float*)d_in[4];
  const float* Wk = (const float*)d_in[5];
  const float* Wv = (const float*)d_in[6];
  const float* Wo = (const float*)d_in[7];
  float* out = (float*)d_out;

  const size_t NT = 4096 * 1024;
  const size_t NW = 1024 * 1024;
  bf16* p = (bf16*)d_ws;
  bf16* qb = p;  p += NT;
  bf16* kb = p;  p += NT;
  bf16* vb = p;  p += NT;
  bf16* Wqb = p; p += NW;
  bf16* Wkb = p; p += NW;
  bf16* Wvb = p; p += NW;
  bf16* Wob = p; p += NW;
  bf16* Qh = p;  p += NT;
  bf16* Kh = p;  p += NT;
  bf16* Vt = p;  p += NT;
  bf16* Oh = p;  p += NT;

  cast_multi<<<2048, 256, 0, stream>>>(q, k, v, nullptr, qb, kb, vb, nullptr,
                                       (int)(NT / 4), 3);
  cast_multi<<<1024, 256, 0, stream>>>(Wq, Wk, Wv, Wo, Wqb, Wkb, Wvb, Wob,
                                       (int)(NW / 4), 4);
  qkv_proj<<<dim3(24, 32), 256, 0, stream>>>(qb, kb, vb, Wqb, Wkb, Wvb, Qh, Kh, Vt);
  attn_fwd<<<512, 256, 0, stream>>>(Qh, Kh, Vt, mask, Oh);
  gemm_o<<<dim3(16, 32), 256, 0, stream>>>(Oh, Wob, out);
}

// Round 5
// 223.942 us; speedup vs baseline: 1.7742x; 1.0415x over previous
//
#include <hip/hip_runtime.h>
#include <hip/hip_bf16.h>
#include <stdint.h>

using bf16 = __hip_bfloat16;
typedef __attribute__((ext_vector_type(8))) short short8;      // 8 bf16 MFMA frag
typedef __attribute__((ext_vector_type(4))) float f32x4;
typedef __attribute__((ext_vector_type(16))) float f32x16;
typedef __attribute__((ext_vector_type(4))) float float4v;
typedef __attribute__((ext_vector_type(4))) unsigned short us4;
typedef __attribute__((ext_vector_type(4))) uint32_t u32x4;

#define LDS_U32 __attribute__((address_space(3))) uint32_t
#define GLB_U32 __attribute__((address_space(1))) uint32_t

__device__ __forceinline__ unsigned short f2b(float f) {
  union { float f; uint32_t u; } x; x.f = f;
  uint32_t r = x.u + 0x7FFFu + ((x.u >> 16) & 1u);  // RNE
  return (unsigned short)(r >> 16);
}

// load 8 consecutive fp32, convert to 8 bf16 (RNE via cvt_pk), store 16B to LDS
__device__ __forceinline__ void stage8(const float* __restrict__ src, bf16* dst) {
  float4v x0 = *(const float4v*)src;
  float4v x1 = *(const float4v*)(src + 4);
  uint32_t p0, p1, p2, p3;
  asm("v_cvt_pk_bf16_f32 %0, %1, %2" : "=v"(p0) : "v"(x0.x), "v"(x0.y));
  asm("v_cvt_pk_bf16_f32 %0, %1, %2" : "=v"(p1) : "v"(x0.z), "v"(x0.w));
  asm("v_cvt_pk_bf16_f32 %0, %1, %2" : "=v"(p2) : "v"(x1.x), "v"(x1.y));
  asm("v_cvt_pk_bf16_f32 %0, %1, %2" : "=v"(p3) : "v"(x1.z), "v"(x1.w));
  u32x4 w = {p0, p1, p2, p3};
  *(u32x4*)dst = w;
}

// ---------------- fused QKV projection: 128x128 tiles, fp32 in (reg-staged) ----------
// seg 0: Qh = (q@Wq^T)*SCLE, bf16 row-major [4096,1024]
// seg 1: KF fragment-major: [bh][s>>5][s4][hi][l31][j]  (attn QK A-frags contiguous)
// seg 2: VF fragment-major: [bh][s>>6][n][t][hi][l31][j] (attn PV B-frags contiguous)
__global__ __launch_bounds__(256, 2)
void qkv_proj(const float* __restrict__ Aq, const float* __restrict__ Ak,
              const float* __restrict__ Av,
              const float* __restrict__ Wq, const float* __restrict__ Wk,
              const float* __restrict__ Wv,
              bf16* __restrict__ Qh, bf16* __restrict__ KF, bf16* __restrict__ VF) {
  __shared__ bf16 Alds[128 * 64];
  __shared__ bf16 Blds[128 * 64];
  const int t = threadIdx.x, lane = t & 63, wave = t >> 6;
  const int l15 = lane & 15, l4 = lane >> 4;
  const int seg = blockIdx.x >> 3;
  const int n0 = (blockIdx.x & 7) * 128;
  const int m0 = blockIdx.y * 128;
  const float* A = (seg == 0) ? Aq : (seg == 1) ? Ak : Av;
  const float* B = (seg == 0) ? Wq : (seg == 1) ? Wk : Wv;
  const int K = 1024;
  const int wr = (wave >> 1) * 64, wc = (wave & 1) * 64;
  const float SCLE = 0.18033688011112042f;  // (1/sqrt(64))*log2(e), folded into Q

  f32x4 acc[4][4] = {};

  for (int kt = 0; kt < K; kt += 64) {
#pragma unroll
    for (int i = 0; i < 4; ++i) {
      int f = i * 256 + t, row = f >> 3, cc = f & 7, ch = cc ^ (row & 7);
      stage8(A + (size_t)(m0 + row) * K + kt + cc * 8, Alds + row * 64 + ch * 8);
      stage8(B + (size_t)(n0 + row) * K + kt + cc * 8, Blds + row * 64 + ch * 8);
    }
    __syncthreads();
#pragma unroll
    for (int ks = 0; ks < 2; ++ks) {
      short8 af[4], bfr[4];
#pragma unroll
      for (int mi = 0; mi < 4; ++mi) {
        int row = wr + mi * 16 + l15;
        int ch = (ks * 4 + l4) ^ (row & 7);
        af[mi] = *(const short8*)(Alds + row * 64 + ch * 8);
      }
#pragma unroll
      for (int ni = 0; ni < 4; ++ni) {
        int row = wc + ni * 16 + l15;
        int ch = (ks * 4 + l4) ^ (row & 7);
        bfr[ni] = *(const short8*)(Blds + row * 64 + ch * 8);
      }
#pragma unroll
      for (int mi = 0; mi < 4; ++mi)
#pragma unroll
        for (int ni = 0; ni < 4; ++ni)
          acc[mi][ni] = __builtin_amdgcn_mfma_f32_16x16x32_bf16(
              af[mi], bfr[ni], acc[mi][ni], 0, 0, 0);
    }
    __syncthreads();
  }

#pragma unroll
  for (int mi = 0; mi < 4; ++mi) {
#pragma unroll
    for (int ni = 0; ni < 4; ++ni) {
      int rbase = m0 + wr + mi * 16 + l4 * 4;
      int col = n0 + wc + ni * 16 + l15;
      if (seg == 0) {
        unsigned short* C = (unsigned short*)Qh;
#pragma unroll
        for (int r = 0; r < 4; ++r)
          C[(size_t)(rbase + r) * 1024 + col] = f2b(acc[mi][ni][r] * SCLE);
      } else if (seg == 1) {
        // KF[bh][s>>5][d>>4][ (d>>3)&1 ][s&31][d&7]
        unsigned short* C = (unsigned short*)KF;
        int h = col >> 6, d = col & 63;
#pragma unroll
        for (int r = 0; r < 4; ++r) {
          int row = rbase + r;
          int b = row >> 11, s = row & 2047;
          size_t idx = (size_t)(b * 16 + h) * 131072 +
                       ((((s >> 5) * 4 + (d >> 4)) * 2 + ((d >> 3) & 1)) * 256) +
                       (s & 31) * 8 + (d & 7);
          C[idx] = f2b(acc[mi][ni][r]);
        }
      } else {
        // VF[bh][s>>6][ (d>>5)&1 ][ (s>>4)&3 ][ (s>>3)&1 ][d&31][s&7]; 4 consec s -> us4
        unsigned short* C = (unsigned short*)VF;
        int h = col >> 6, d = col & 63;
        int row = rbase;
        int b = row >> 11, s = row & 2047;
        size_t idx = (size_t)(b * 16 + h) * 131072 +
                     (((((s >> 6) * 2 + ((d >> 5) & 1)) * 4 + ((s >> 4) & 3)) * 2 +
                       ((s >> 3) & 1)) * 256) +
                     (d & 31) * 8 + (s & 7);
        us4 y;
        y.x = f2b(acc[mi][ni][0]); y.y = f2b(acc[mi][ni][1]);
        y.z = f2b(acc[mi][ni][2]); y.w = f2b(acc[mi][ni][3]);
        *(us4*)(C + idx) = y;
      }
    }
  }
}

// ---------------- output projection: A bf16 (gload_lds), B=Wo fp32 reg-staged ------
__global__ __launch_bounds__(256, 2)
void gemm_o(const bf16* __restrict__ A, const float* __restrict__ B,
            float* __restrict__ C) {
  __shared__ bf16 Alds[128 * 64];
  __shared__ bf16 Blds[64 * 64];
  const int t = threadIdx.x, lane = t & 63, wave = t >> 6;
  const int l15 = lane & 15, l4 = lane >> 4;
  const int n0 = blockIdx.x * 64, m0 = blockIdx.y * 128;
  const int K = 1024;
  const int wr = (wave >> 1) * 64, wc = (wave & 1) * 32;

  f32x4 acc[4][2] = {};

  for (int kt = 0; kt < K; kt += 64) {
#pragma unroll
    for (int i = 0; i < 4; ++i) {
      int f = i * 256 + t, row = f >> 3, csrc = (f & 7) ^ (row & 7);
      __builtin_amdgcn_global_load_lds(
          (const GLB_U32*)(A + (size_t)(m0 + row) * K + kt + csrc * 8),
          (LDS_U32*)(Alds + f * 8), 16, 0, 0);
    }
#pragma unroll
    for (int i = 0; i < 2; ++i) {
      int f = i * 256 + t, row = f >> 3, cc = f & 7, ch = cc ^ (row & 7);
      stage8(B + (size_t)(n0 + row) * K + kt + cc * 8, Blds + row * 64 + ch * 8);
    }
    __syncthreads();
#pragma unroll
    for (int ks = 0; ks < 2; ++ks) {
      short8 af[4], bfr[2];
#pragma unroll
      for (int mi = 0; mi < 4; ++mi) {
        int row = wr + mi * 16 + l15;
        int ch = (ks * 4 + l4) ^ (row & 7);
        af[mi] = *(const short8*)(Alds + row * 64 + ch * 8);
      }
#pragma unroll
      for (int ni = 0; ni < 2; ++ni) {
        int row = wc + ni * 16 + l15;
        int ch = (ks * 4 + l4) ^ (row & 7);
        bfr[ni] = *(const short8*)(Blds + row * 64 + ch * 8);
      }
#pragma unroll
      for (int mi = 0; mi < 4; ++mi)
#pragma unroll
        for (int ni = 0; ni < 2; ++ni)
          acc[mi][ni] = __builtin_amdgcn_mfma_f32_16x16x32_bf16(
              af[mi], bfr[ni], acc[mi][ni], 0, 0, 0);
    }
    __syncthreads();
  }

#pragma unroll
  for (int mi = 0; mi < 4; ++mi)
#pragma unroll
    for (int ni = 0; ni < 2; ++ni) {
      int rbase = m0 + wr + mi * 16 + l4 * 4;
      int col = n0 + wc + ni * 16 + l15;
#pragma unroll
      for (int r = 0; r < 4; ++r)
        C[(size_t)(rbase + r) * 1024 + col] = acc[mi][ni][r];
    }
}

// ---------------- causal flash attention: swapped QK^T, fragment-major K/V --------
__global__ __launch_bounds__(256, 2)
void attn_fwd(const bf16* __restrict__ Q, const bf16* __restrict__ KF,
              const bf16* __restrict__ VF, const int* __restrict__ mask,
              bf16* __restrict__ O) {
  const int lin = blockIdx.x;
  const int xcd = lin & 7, q8 = lin >> 3;
  const int bh = xcd + 8 * (q8 & 3), g = q8 >> 2;   // same head -> same XCD (L2)
  const int b = bh >> 4, h = bh & 15;
  const int wave = threadIdx.x >> 6, lane = threadIdx.x & 63;
  const int l31 = lane & 31, hi = lane >> 5;
  const int job = 2 * g + (wave >> 1);              // 0..31
  const int halfk = wave & 1, wp = wave >> 1;

  __shared__ float accL[2][64][33];
  __shared__ float mlL[2][64][2];

  const size_t bqk = (size_t)b * 2048 * 1024 + h * 64;
  const size_t fbase = (size_t)bh * 131072;  // KF/VF per-head base

  for (int si = 0; si < 2; ++si) {
    const int s = si ? (63 - job) : job;   // strip: 32 q-rows
    const int q0 = 32 * s;
    const int T = (s >> 1) + 1;
    const int hsplit = (T + 1) >> 1;
    const int tstart = halfk ? hsplit : 0;
    const int tend = halfk ? T : hsplit;

    short8 qf[4];
#pragma unroll
    for (int s4 = 0; s4 < 4; ++s4)
      qf[s4] = *(const short8*)(Q + bqk + (size_t)(q0 + l31) * 1024 + 16 * s4 + 8 * hi);

    // once-per-strip pad-mask scan (all-ones fast path)
    int anyz = 0;
    for (int i = tstart * 64 + lane; i < tend * 64; i += 64)
      anyz |= (mask[b * 2048 + i] == 0);
    const bool doMask = __any(anyz);

    f32x16 acc0 = {}, acc1 = {};
    float m = -1e30f, l = 0.f;

    short8 kf[2][4], kn[2][4], vf[2][4];
    if (tstart < tend) {
#pragma unroll
      for (int u = 0; u < 2; ++u)
#pragma unroll
        for (int s4 = 0; s4 < 4; ++s4)
          kf[u][s4] = *(const short8*)(KF + fbase +
              ((size_t)((2 * tstart + u) * 4 + s4) * 2 + hi) * 256 + l31 * 8);
    }

    for (int tt = tstart; tt < tend; ++tt) {
      // V frags issued early (consumed after softmax)
#pragma unroll
      for (int n = 0; n < 2; ++n)
#pragma unroll
        for (int tq = 0; tq < 4; ++tq)
          vf[n][tq] = *(const short8*)(VF + fbase +
              ((size_t)(((tt * 2 + n) * 4 + tq) * 2 + hi)) * 256 + l31 * 8);

      f32x16 s0 = {}, s1 = {};
      __builtin_amdgcn_s_setprio(1);
#pragma unroll
      for (int s4 = 0; s4 < 4; ++s4) {
        s0 = __builtin_amdgcn_mfma_f32_32x32x16_bf16(kf[0][s4], qf[s4], s0, 0, 0, 0);
        s1 = __builtin_amdgcn_mfma_f32_32x32x16_bf16(kf[1][s4], qf[s4], s1, 0, 0, 0);
      }
      __builtin_amdgcn_s_setprio(0);
      if (tt + 1 < tend) {  // K prefetch for next tile
#pragma unroll
        for (int u = 0; u < 2; ++u)
#pragma unroll
          for (int s4 = 0; s4 < 4; ++s4)
            kn[u][s4] = *(const short8*)(KF + fbase +
                ((size_t)((2 * (tt + 1) + u) * 4 + s4) * 2 + hi) * 256 + l31 * 8);
      }

      float w[2][16];
#pragma unroll
      for (int p = 0; p < 16; ++p) { w[0][p] = s0[p]; w[1][p] = s1[p]; }

      if (doMask) {  // pad-mask path (wave-uniform branch)
        int mv = mask[b * 2048 + tt * 64 + lane];
        uint64_t bits = __ballot(mv != 0);
        uint64_t bs = bits >> (4 * hi);
#pragma unroll
        for (int u = 0; u < 2; ++u)
#pragma unroll
          for (int p = 0; p < 16; ++p)
            if (!((bs >> (32 * u + (p & 3) + 8 * (p >> 2))) & 1)) w[u][p] = -3e38f;
      }
      if (tt == T - 1) {  // causal clamp, diagonal tile only
        int qr = 32 * (s & 1) + l31 - 4 * hi;
#pragma unroll
        for (int u = 0; u < 2; ++u)
#pragma unroll
          for (int p = 0; p < 16; ++p)
            if (32 * u + (p & 3) + 8 * (p >> 2) > qr) w[u][p] = -3e38f;
      }

      float tm = fmaxf(w[0][0], w[1][0]);
#pragma unroll
      for (int p = 1; p < 16; ++p) tm = fmaxf(tm, fmaxf(w[0][p], w[1][p]));
      tm = fmaxf(tm, __shfl_xor(tm, 32));

      // defer-max (T13)
      if (!__all(tm <= m + 8.f)) {
        float mn = fmaxf(m, tm);
        float corr = __builtin_amdgcn_exp2f(m - mn);
        m = mn; l *= corr;
#pragma unroll
        for (int p = 0; p < 16; ++p) {
          float ct = __shfl(corr, (p & 3) + 8 * (p >> 2) + 4 * hi);
          acc0[p] *= ct; acc1[p] *= ct;
        }
      }

      float ts = 0.f;
#pragma unroll
      for (int u = 0; u < 2; ++u)
#pragma unroll
        for (int p = 0; p < 16; ++p) {
          float pv = __builtin_amdgcn_exp2f(w[u][p] - m);
          w[u][p] = pv; ts += pv;
        }
      ts += __shfl_xor(ts, 32);
      l += ts;

      // pack P to bf16 pairs (T12)
      uint32_t pkk[2][8];
#pragma unroll
      for (int u = 0; u < 2; ++u)
#pragma unroll
        for (int a = 0; a < 4; ++a)
#pragma unroll
          for (int w2 = 0; w2 < 2; ++w2) {
            uint32_t r;
            asm("v_cvt_pk_bf16_f32 %0, %1, %2"
                : "=v"(r) : "v"(w[u][4 * a + 2 * w2]), "v"(w[u][4 * a + 2 * w2 + 1]));
            pkk[u][2 * a + w2] = r;
          }

      // PV A-frags via permlane32_swap (1 swap fills 2 words), then 8 PV MFMAs
#pragma unroll
      for (int tq = 0; tq < 4; ++tq) {
        const int u = tq >> 1, alo = 2 * (tq & 1);
        uint32_t a0 = pkk[u][2 * alo + 0], b0 = pkk[u][2 * alo + 2];
        uint32_t a1 = pkk[u][2 * alo + 1], b1 = pkk[u][2 * alo + 3];
        asm("v_permlane32_swap_b32 %0, %1" : "+v"(a0), "+v"(b0));
        asm("v_permlane32_swap_b32 %0, %1" : "+v"(a1), "+v"(b1));
        u32x4 wv = {a0, a1, b0, b1};
        short8 paf = __builtin_bit_cast(short8, wv);
        __builtin_amdgcn_s_setprio(1);
        acc0 = __builtin_amdgcn_mfma_f32_32x32x16_bf16(paf, vf[0][tq], acc0, 0, 0, 0);
        acc1 = __builtin_amdgcn_mfma_f32_32x32x16_bf16(paf, vf[1][tq], acc1, 0, 0, 0);
        __builtin_amdgcn_s_setprio(0);
      }

#pragma unroll
      for (int u = 0; u < 2; ++u)
#pragma unroll
        for (int s4 = 0; s4 < 4; ++s4) kf[u][s4] = kn[u][s4];
    }

    // ---- split-K merge ----
    if (halfk) {
#pragma unroll
      for (int p = 0; p < 16; ++p) {
        accL[wp][lane][p] = acc0[p];
        accL[wp][lane][16 + p] = acc1[p];
      }
      mlL[wp][lane][0] = m; mlL[wp][lane][1] = l;
    }
    __syncthreads();
    if (!halfk) {
      float mB = mlL[wp][lane][0], lB = mlL[wp][lane][1];
      float ms = fmaxf(m, mB);
      float cAr = __builtin_amdgcn_exp2f(m - ms);
      float cBr = __builtin_amdgcn_exp2f(mB - ms);
      float inv = 1.f / (cAr * l + cBr * lB);
      float fa = cAr * inv, fb = cBr * inv;
      unsigned short* Ou = (unsigned short*)O;
#pragma unroll
      for (int p = 0; p < 16; ++p) {
        int crow = (p & 3) + 8 * (p >> 2) + 4 * hi;
        float faT = __shfl(fa, crow);
        float fbT = __shfl(fb, crow);
        float o0 = acc0[p] * faT + accL[wp][lane][p] * fbT;
        float o1 = acc1[p] * faT + accL[wp][lane][16 + p] * fbT;
        size_t ro = (size_t)(b * 2048 + q0 + crow) * 1024 + h * 64;
        Ou[ro + l31] = f2b(o0);
        Ou[ro + 32 + l31] = f2b(o1);
      }
    }
    __syncthreads();
  }
}

// ---------------- launch ----------------
extern "C" void kernel_launch(void* const* d_in, const int* in_sizes, int n_in,
                              void* d_out, int out_size, void* d_ws, size_t ws_size,
                              hipStream_t stream) {
  const float* q = (const float*)d_in[0];
  const float* k = (const float*)d_in[1];
  const float* v = (const float*)d_in[2];
  const int* mask = (const int*)d_in[3];
  const float* Wq = (const float*)d_in[4];
  const float* Wk = (const float*)d_in[5];
  const float* Wv = (const float*)d_in[6];
  const float* Wo = (const float*)d_in[7];
  float* out = (float*)d_out;

  const size_t NT = 4096 * 1024;
  bf16* p = (bf16*)d_ws;
  bf16* Qh = p; p += NT;
  bf16* KF = p; p += NT;
  bf16* VF = p; p += NT;
  bf16* Oh = p; p += NT;

  qkv_proj<<<dim3(24, 32), 256, 0, stream>>>(q, k, v, Wq, Wk, Wv, Qh, KF, VF);
  attn_fwd<<<512, 256, 0, stream>>>(Qh, KF, VF, mask, Oh);
  gemm_o<<<dim3(16, 32), 256, 0, stream>>>(Oh, Wo, out);
}

// Round 6
// 201.698 us; speedup vs baseline: 1.9699x; 1.1103x over previous
//
#include <hip/hip_runtime.h>
#include <hip/hip_bf16.h>
#include <stdint.h>

using bf16 = __hip_bfloat16;
typedef __attribute__((ext_vector_type(8))) short short8;      // 8 bf16 MFMA frag
typedef __attribute__((ext_vector_type(4))) float f32x4;
typedef __attribute__((ext_vector_type(16))) float f32x16;
typedef __attribute__((ext_vector_type(4))) float float4v;
typedef __attribute__((ext_vector_type(4))) unsigned short us4;
typedef __attribute__((ext_vector_type(4))) uint32_t u32x4;
typedef __attribute__((ext_vector_type(2))) uint32_t u32x2;

#define LDS_U32 __attribute__((address_space(3))) uint32_t
#define GLB_U32 __attribute__((address_space(1))) uint32_t

__device__ __forceinline__ unsigned short f2b(float f) {
  union { float f; uint32_t u; } x; x.f = f;
  uint32_t r = x.u + 0x7FFFu + ((x.u >> 16) & 1u);  // RNE
  return (unsigned short)(r >> 16);
}

// ---------------- fp32 -> bf16 cast: q,k,v + 4 weights in one launch ----------------
__global__ void cast_all(const float* __restrict__ q, const float* __restrict__ k,
                         const float* __restrict__ v, const float* __restrict__ Wq,
                         const float* __restrict__ Wk, const float* __restrict__ Wv,
                         const float* __restrict__ Wo,
                         bf16* __restrict__ qb, bf16* __restrict__ kb,
                         bf16* __restrict__ vb, bf16* __restrict__ Wqb,
                         bf16* __restrict__ Wkb, bf16* __restrict__ Wvb,
                         bf16* __restrict__ Wob) {
  const int NQ = 1 << 20;   // float4 vecs per q/k/v (4M floats)
  const int NW = 1 << 18;   // float4 vecs per weight (1M floats)
  const int total = 3 * NQ + 4 * NW;
  for (int i = blockIdx.x * blockDim.x + threadIdx.x; i < total;
       i += gridDim.x * blockDim.x) {
    const float* s; bf16* d; int vi;
    if (i < 3 * NQ) {
      int a = i >> 20; vi = i & (NQ - 1);
      s = (a == 0) ? q : (a == 1) ? k : v;
      d = (a == 0) ? qb : (a == 1) ? kb : vb;
    } else {
      int j = i - 3 * NQ;
      int a = j >> 18; vi = j & (NW - 1);
      s = (a == 0) ? Wq : (a == 1) ? Wk : (a == 2) ? Wv : Wo;
      d = (a == 0) ? Wqb : (a == 1) ? Wkb : (a == 2) ? Wvb : Wob;
    }
    float4v x = ((const float4v*)s)[vi];
    us4 y;
    y.x = f2b(x.x); y.y = f2b(x.y); y.z = f2b(x.z); y.w = f2b(x.w);
    ((us4*)d)[vi] = y;
  }
}

// ---------------- fused QKV projection: 128x128 tiles, bf16 gload_lds ----------------
// XCD-chunked grid: physical p -> logical l=(p%8)*96+p/8; l = (seg*32+m)*8+n.
// seg 0: Qh = (q@Wq^T)*SCLE bf16 [4096,1024]; seg 1: KF frag-major; seg 2: VF frag-major.
__global__ __launch_bounds__(256, 2)
void qkv_proj(const bf16* __restrict__ Aq, const bf16* __restrict__ Ak,
              const bf16* __restrict__ Av,
              const bf16* __restrict__ Wq, const bf16* __restrict__ Wk,
              const bf16* __restrict__ Wv,
              bf16* __restrict__ Qh, bf16* __restrict__ KF, bf16* __restrict__ VF) {
  __shared__ bf16 Alds[128 * 64];
  __shared__ bf16 Blds[128 * 64];
  const int t = threadIdx.x, lane = t & 63, wave = t >> 6;
  const int l15 = lane & 15, l4 = lane >> 4;
  const int p = blockIdx.x;
  const int l = (p & 7) * 96 + (p >> 3);       // contiguous 96-block chunk per XCD
  const int grp = l >> 3;                       // seg*32 + m
  const int n0 = (l & 7) * 128;
  const int seg = grp >> 5;
  const int m0 = (grp & 31) * 128;
  const bf16* A = (seg == 0) ? Aq : (seg == 1) ? Ak : Av;
  const bf16* B = (seg == 0) ? Wq : (seg == 1) ? Wk : Wv;
  const int K = 1024;
  const int wr = (wave >> 1) * 64, wc = (wave & 1) * 64;
  const float SCLE = 0.18033688011112042f;  // (1/sqrt(64))*log2(e), folded into Q

  f32x4 acc[4][4] = {};

  for (int kt = 0; kt < K; kt += 64) {
#pragma unroll
    for (int i = 0; i < 4; ++i) {
      int f = i * 256 + t, row = f >> 3, csrc = (f & 7) ^ (row & 7);
      __builtin_amdgcn_global_load_lds(
          (const GLB_U32*)(A + (size_t)(m0 + row) * K + kt + csrc * 8),
          (LDS_U32*)(Alds + f * 8), 16, 0, 0);
      __builtin_amdgcn_global_load_lds(
          (const GLB_U32*)(B + (size_t)(n0 + row) * K + kt + csrc * 8),
          (LDS_U32*)(Blds + f * 8), 16, 0, 0);
    }
    __syncthreads();
#pragma unroll
    for (int ks = 0; ks < 2; ++ks) {
      short8 af[4], bfr[4];
#pragma unroll
      for (int mi = 0; mi < 4; ++mi) {
        int row = wr + mi * 16 + l15;
        int ch = (ks * 4 + l4) ^ (row & 7);
        af[mi] = *(const short8*)(Alds + row * 64 + ch * 8);
      }
#pragma unroll
      for (int ni = 0; ni < 4; ++ni) {
        int row = wc + ni * 16 + l15;
        int ch = (ks * 4 + l4) ^ (row & 7);
        bfr[ni] = *(const short8*)(Blds + row * 64 + ch * 8);
      }
#pragma unroll
      for (int mi = 0; mi < 4; ++mi)
#pragma unroll
        for (int ni = 0; ni < 4; ++ni)
          acc[mi][ni] = __builtin_amdgcn_mfma_f32_16x16x32_bf16(
              af[mi], bfr[ni], acc[mi][ni], 0, 0, 0);
    }
    __syncthreads();
  }

#pragma unroll
  for (int mi = 0; mi < 4; ++mi) {
#pragma unroll
    for (int ni = 0; ni < 4; ++ni) {
      int rbase = m0 + wr + mi * 16 + l4 * 4;
      int col = n0 + wc + ni * 16 + l15;
      if (seg == 0) {
        unsigned short* C = (unsigned short*)Qh;
#pragma unroll
        for (int r = 0; r < 4; ++r)
          C[(size_t)(rbase + r) * 1024 + col] = f2b(acc[mi][ni][r] * SCLE);
      } else if (seg == 1) {
        // KF[bh][s>>5][d>>4][(d>>3)&1][s&31][d&7]
        unsigned short* C = (unsigned short*)KF;
        int h = col >> 6, d = col & 63;
#pragma unroll
        for (int r = 0; r < 4; ++r) {
          int row = rbase + r;
          int b = row >> 11, s = row & 2047;
          size_t idx = (size_t)(b * 16 + h) * 131072 +
                       ((((s >> 5) * 4 + (d >> 4)) * 2 + ((d >> 3) & 1)) * 256) +
                       (s & 31) * 8 + (d & 7);
          C[idx] = f2b(acc[mi][ni][r]);
        }
      } else {
        // VF[bh][s>>6][(d>>5)&1][(s>>4)&3][(s>>3)&1][d&31][s&7]; 4 consec s -> us4
        unsigned short* C = (unsigned short*)VF;
        int h = col >> 6, d = col & 63;
        int row = rbase;
        int b = row >> 11, s = row & 2047;
        size_t idx = (size_t)(b * 16 + h) * 131072 +
                     (((((s >> 6) * 2 + ((d >> 5) & 1)) * 4 + ((s >> 4) & 3)) * 2 +
                       ((s >> 3) & 1)) * 256) +
                     (d & 31) * 8 + (s & 7);
        us4 y;
        y.x = f2b(acc[mi][ni][0]); y.y = f2b(acc[mi][ni][1]);
        y.z = f2b(acc[mi][ni][2]); y.w = f2b(acc[mi][ni][3]);
        *(us4*)(C + idx) = y;
      }
    }
  }
}

// ---------------- output projection: 128x64 tiles, bf16 gload_lds both, XCD-chunked --
__global__ __launch_bounds__(256, 2)
void gemm_o(const bf16* __restrict__ A, const bf16* __restrict__ B,
            float* __restrict__ C) {
  __shared__ bf16 Alds[128 * 64];
  __shared__ bf16 Blds[64 * 64];
  const int t = threadIdx.x, lane = t & 63, wave = t >> 6;
  const int l15 = lane & 15, l4 = lane >> 4;
  const int p = blockIdx.x;
  const int l = (p & 7) * 64 + (p >> 3);       // 64-block chunk per XCD
  const int m0 = (l >> 4) * 128;
  const int n0 = (l & 15) * 64;
  const int K = 1024;
  const int wr = (wave >> 1) * 64, wc = (wave & 1) * 32;

  f32x4 acc[4][2] = {};

  for (int kt = 0; kt < K; kt += 64) {
#pragma unroll
    for (int i = 0; i < 4; ++i) {
      int f = i * 256 + t, row = f >> 3, csrc = (f & 7) ^ (row & 7);
      __builtin_amdgcn_global_load_lds(
          (const GLB_U32*)(A + (size_t)(m0 + row) * K + kt + csrc * 8),
          (LDS_U32*)(Alds + f * 8), 16, 0, 0);
    }
#pragma unroll
    for (int i = 0; i < 2; ++i) {
      int f = i * 256 + t, row = f >> 3, csrc = (f & 7) ^ (row & 7);
      __builtin_amdgcn_global_load_lds(
          (const GLB_U32*)(B + (size_t)(n0 + row) * K + kt + csrc * 8),
          (LDS_U32*)(Blds + f * 8), 16, 0, 0);
    }
    __syncthreads();
#pragma unroll
    for (int ks = 0; ks < 2; ++ks) {
      short8 af[4], bfr[2];
#pragma unroll
      for (int mi = 0; mi < 4; ++mi) {
        int row = wr + mi * 16 + l15;
        int ch = (ks * 4 + l4) ^ (row & 7);
        af[mi] = *(const short8*)(Alds + row * 64 + ch * 8);
      }
#pragma unroll
      for (int ni = 0; ni < 2; ++ni) {
        int row = wc + ni * 16 + l15;
        int ch = (ks * 4 + l4) ^ (row & 7);
        bfr[ni] = *(const short8*)(Blds + row * 64 + ch * 8);
      }
#pragma unroll
      for (int mi = 0; mi < 4; ++mi)
#pragma unroll
        for (int ni = 0; ni < 2; ++ni)
          acc[mi][ni] = __builtin_amdgcn_mfma_f32_16x16x32_bf16(
              af[mi], bfr[ni], acc[mi][ni], 0, 0, 0);
    }
    __syncthreads();
  }

#pragma unroll
  for (int mi = 0; mi < 4; ++mi)
#pragma unroll
    for (int ni = 0; ni < 2; ++ni) {
      int rbase = m0 + wr + mi * 16 + l4 * 4;
      int col = n0 + wc + ni * 16 + l15;
#pragma unroll
      for (int r = 0; r < 4; ++r)
        C[(size_t)(rbase + r) * 1024 + col] = acc[mi][ni][r];
    }
}

// ---------------- causal flash attention: swapped QK^T, fragment-major K/V --------
__global__ __launch_bounds__(256, 2)
void attn_fwd(const bf16* __restrict__ Q, const bf16* __restrict__ KF,
              const bf16* __restrict__ VF, const int* __restrict__ mask,
              bf16* __restrict__ O) {
  const int lin = blockIdx.x;
  const int xcd = lin & 7, q8 = lin >> 3;
  const int bh = xcd + 8 * (q8 & 3), g = q8 >> 2;   // same head -> same XCD (L2)
  const int b = bh >> 4, h = bh & 15;
  const int wave = threadIdx.x >> 6, lane = threadIdx.x & 63;
  const int l31 = lane & 31, hi = lane >> 5;
  const int job = 2 * g + (wave >> 1);              // 0..31
  const int halfk = wave & 1, wp = wave >> 1;

  __shared__ float accL[2][64][33];
  __shared__ float mlL[2][64][2];

  const size_t bqk = (size_t)b * 2048 * 1024 + h * 64;
  const size_t fbase = (size_t)bh * 131072;  // KF/VF per-head base

  for (int si = 0; si < 2; ++si) {
    const int s = si ? (63 - job) : job;   // strip: 32 q-rows
    const int q0 = 32 * s;
    const int T = (s >> 1) + 1;
    const int hsplit = (T + 1) >> 1;
    const int tstart = halfk ? hsplit : 0;
    const int tend = halfk ? T : hsplit;

    short8 qf[4];
#pragma unroll
    for (int s4 = 0; s4 < 4; ++s4)
      qf[s4] = *(const short8*)(Q + bqk + (size_t)(q0 + l31) * 1024 + 16 * s4 + 8 * hi);

    // once-per-strip pad-mask scan (all-ones fast path)
    int anyz = 0;
    for (int i = tstart * 64 + lane; i < tend * 64; i += 64)
      anyz |= (mask[b * 2048 + i] == 0);
    const bool doMask = __any(anyz);

    f32x16 acc0 = {}, acc1 = {};
    float m = -1e30f, l = 0.f;

    short8 kf[2][4], kn[2][4], vf[2][4];
    if (tstart < tend) {
#pragma unroll
      for (int u = 0; u < 2; ++u)
#pragma unroll
        for (int s4 = 0; s4 < 4; ++s4)
          kf[u][s4] = *(const short8*)(KF + fbase +
              ((size_t)((2 * tstart + u) * 4 + s4) * 2 + hi) * 256 + l31 * 8);
    }

    for (int tt = tstart; tt < tend; ++tt) {
#pragma unroll
      for (int n = 0; n < 2; ++n)
#pragma unroll
        for (int tq = 0; tq < 4; ++tq)
          vf[n][tq] = *(const short8*)(VF + fbase +
              ((size_t)(((tt * 2 + n) * 4 + tq) * 2 + hi)) * 256 + l31 * 8);

      f32x16 s0 = {}, s1 = {};
      __builtin_amdgcn_s_setprio(1);
#pragma unroll
      for (int s4 = 0; s4 < 4; ++s4) {
        s0 = __builtin_amdgcn_mfma_f32_32x32x16_bf16(kf[0][s4], qf[s4], s0, 0, 0, 0);
        s1 = __builtin_amdgcn_mfma_f32_32x32x16_bf16(kf[1][s4], qf[s4], s1, 0, 0, 0);
      }
      __builtin_amdgcn_s_setprio(0);
      if (tt + 1 < tend) {  // K prefetch for next tile
#pragma unroll
        for (int u = 0; u < 2; ++u)
#pragma unroll
          for (int s4 = 0; s4 < 4; ++s4)
            kn[u][s4] = *(const short8*)(KF + fbase +
                ((size_t)((2 * (tt + 1) + u) * 4 + s4) * 2 + hi) * 256 + l31 * 8);
      }

      float w[2][16];
#pragma unroll
      for (int p = 0; p < 16; ++p) { w[0][p] = s0[p]; w[1][p] = s1[p]; }

      if (doMask) {  // pad-mask path (wave-uniform branch)
        int mv = mask[b * 2048 + tt * 64 + lane];
        uint64_t bits = __ballot(mv != 0);
        uint64_t bs = bits >> (4 * hi);
#pragma unroll
        for (int u = 0; u < 2; ++u)
#pragma unroll
          for (int p = 0; p < 16; ++p)
            if (!((bs >> (32 * u + (p & 3) + 8 * (p >> 2))) & 1)) w[u][p] = -3e38f;
      }
      if (tt == T - 1) {  // causal clamp, diagonal tile only
        int qr = 32 * (s & 1) + l31 - 4 * hi;
#pragma unroll
        for (int u = 0; u < 2; ++u)
#pragma unroll
          for (int p = 0; p < 16; ++p)
            if (32 * u + (p & 3) + 8 * (p >> 2) > qr) w[u][p] = -3e38f;
      }

      float tm = fmaxf(w[0][0], w[1][0]);
#pragma unroll
      for (int p = 1; p < 16; ++p) tm = fmaxf(tm, fmaxf(w[0][p], w[1][p]));
      tm = fmaxf(tm, __shfl_xor(tm, 32));

      // defer-max (T13)
      if (!__all(tm <= m + 8.f)) {
        float mn = fmaxf(m, tm);
        float corr = __builtin_amdgcn_exp2f(m - mn);
        m = mn; l *= corr;
#pragma unroll
        for (int p = 0; p < 16; ++p) {
          float ct = __shfl(corr, (p & 3) + 8 * (p >> 2) + 4 * hi);
          acc0[p] *= ct; acc1[p] *= ct;
        }
      }

      float ts = 0.f;
#pragma unroll
      for (int u = 0; u < 2; ++u)
#pragma unroll
        for (int p = 0; p < 16; ++p) {
          float pv = __builtin_amdgcn_exp2f(w[u][p] - m);
          w[u][p] = pv; ts += pv;
        }
      ts += __shfl_xor(ts, 32);
      l += ts;

      // pack P to bf16 pairs (T12)
      uint32_t pkk[2][8];
#pragma unroll
      for (int u = 0; u < 2; ++u)
#pragma unroll
        for (int a = 0; a < 4; ++a)
#pragma unroll
          for (int w2 = 0; w2 < 2; ++w2) {
            uint32_t r;
            asm("v_cvt_pk_bf16_f32 %0, %1, %2"
                : "=v"(r) : "v"(w[u][4 * a + 2 * w2]), "v"(w[u][4 * a + 2 * w2 + 1]));
            pkk[u][2 * a + w2] = r;
          }

      // PV A-frags via permlane32_swap, then 8 PV MFMAs
#pragma unroll
      for (int tq = 0; tq < 4; ++tq) {
        const int u = tq >> 1, alo = 2 * (tq & 1);
        uint32_t a0 = pkk[u][2 * alo + 0], b0 = pkk[u][2 * alo + 2];
        uint32_t a1 = pkk[u][2 * alo + 1], b1 = pkk[u][2 * alo + 3];
        asm("v_permlane32_swap_b32 %0, %1" : "+v"(a0), "+v"(b0));
        asm("v_permlane32_swap_b32 %0, %1" : "+v"(a1), "+v"(b1));
        u32x4 wv = {a0, a1, b0, b1};
        short8 paf = __builtin_bit_cast(short8, wv);
        __builtin_amdgcn_s_setprio(1);
        acc0 = __builtin_amdgcn_mfma_f32_32x32x16_bf16(paf, vf[0][tq], acc0, 0, 0, 0);
        acc1 = __builtin_amdgcn_mfma_f32_32x32x16_bf16(paf, vf[1][tq], acc1, 0, 0, 0);
        __builtin_amdgcn_s_setprio(0);
      }

#pragma unroll
      for (int u = 0; u < 2; ++u)
#pragma unroll
        for (int s4 = 0; s4 < 4; ++s4) kf[u][s4] = kn[u][s4];
    }

    // ---- split-K merge ----
    if (halfk) {
#pragma unroll
      for (int p = 0; p < 16; ++p) {
        accL[wp][lane][p] = acc0[p];
        accL[wp][lane][16 + p] = acc1[p];
      }
      mlL[wp][lane][0] = m; mlL[wp][lane][1] = l;
    }
    __syncthreads();
    if (!halfk) {
      float mB = mlL[wp][lane][0], lB = mlL[wp][lane][1];
      float ms = fmaxf(m, mB);
      float cAr = __builtin_amdgcn_exp2f(m - ms);
      float cBr = __builtin_amdgcn_exp2f(mB - ms);
      float inv = 1.f / (cAr * l + cBr * lB);
      float fa = cAr * inv, fb = cBr * inv;
      unsigned short* Ou = (unsigned short*)O;
#pragma unroll
      for (int p = 0; p < 16; ++p) {
        int crow = (p & 3) + 8 * (p >> 2) + 4 * hi;
        float faT = __shfl(fa, crow);
        float fbT = __shfl(fb, crow);
        float o0 = acc0[p] * faT + accL[wp][lane][p] * fbT;
        float o1 = acc1[p] * faT + accL[wp][lane][16 + p] * fbT;
        size_t ro = (size_t)(b * 2048 + q0 + crow) * 1024 + h * 64;
        Ou[ro + l31] = f2b(o0);
        Ou[ro + 32 + l31] = f2b(o1);
      }
    }
    __syncthreads();
  }
}

// ---------------- launch ----------------
extern "C" void kernel_launch(void* const* d_in, const int* in_sizes, int n_in,
                              void* d_out, int out_size, void* d_ws, size_t ws_size,
                              hipStream_t stream) {
  const float* q = (const float*)d_in[0];
  const float* k = (const float*)d_in[1];
  const float* v = (const float*)d_in[2];
  const int* mask = (const int*)d_in[3];
  const float* Wq = (const float*)d_in[4];
  const float* Wk = (const float*)d_in[5];
  const float* Wv = (const float*)d_in[6];
  const float* Wo = (const float*)d_in[7];
  float* out = (float*)d_out;

  const size_t NT = 4096 * 1024;
  const size_t NW = 1024 * 1024;
  bf16* p = (bf16*)d_ws;
  bf16* qb = p;  p += NT;
  bf16* kb = p;  p += NT;
  bf16* vb = p;  p += NT;
  bf16* Wqb = p; p += NW;
  bf16* Wkb = p; p += NW;
  bf16* Wvb = p; p += NW;
  bf16* Wob = p; p += NW;
  bf16* Qh = p;  p += NT;
  bf16* KF = p;  p += NT;
  bf16* VF = p;  p += NT;
  bf16* Oh = p;  p += NT;

  cast_all<<<2048, 256, 0, stream>>>(q, k, v, Wq, Wk, Wv, Wo,
                                     qb, kb, vb, Wqb, Wkb, Wvb, Wob);
  qkv_proj<<<768, 256, 0, stream>>>(qb, kb, vb, Wqb, Wkb, Wvb, Qh, KF, VF);
  attn_fwd<<<512, 256, 0, stream>>>(Qh, KF, VF, mask, Oh);
  gemm_o<<<512, 256, 0, stream>>>(Oh, Wob, out);
}